// Round 5
// baseline (358.391 us; speedup 1.0000x reference)
//
#include <hip/hip_runtime.h>
#include <cstdint>

#define ROW_LEN 4096
#define KSEL 8
#define NT 256
#define EPT 16
#define C0 2.30f      // P(N(0,1)>2.30) ~ 0.0107 -> ~44 candidates per 4096-row
#define WCAP 32       // per-wave candidate capacity (lambda ~ 11/wave)

// order-preserving fp32 -> u32 (monotone; input has no NaN)
__device__ inline unsigned ordkey(float f) {
    int t = __float_as_int(f);
    return (unsigned)(t ^ ((t >> 31) | 0x80000000));
}
__device__ inline float unkey(unsigned u) {
    int t = (int)u;
    return __int_as_float(t < 0 ? (t ^ 0x80000000) : ~t);
}

__global__ __launch_bounds__(NT) void kmax_kernel(const float* __restrict__ in,
                                                  float* __restrict__ out) {
    const int row  = blockIdx.x;
    const int tid  = threadIdx.x;
    const int lane = tid & 63;
    const int wave = tid >> 6;
    const unsigned long long lt = (1ull << lane) - 1ull;

    __shared__ float    cand[4 * WCAP];
    __shared__ unsigned wcnt[4];
    __shared__ unsigned swsum[4];
    __shared__ float    selV[KSEL];
    __shared__ int      selGi[KSEL];
    __shared__ int      selCnt;

    // wave-contiguous loads: instruction j covers a contiguous 1KB per wave
    // slot s=(j,c): global idx gi = j*1024 + tid*4 + c
    const float4* p4 = reinterpret_cast<const float4*>(in + (size_t)row * ROW_LEN);
    float k[EPT];
#pragma unroll
    for (int j = 0; j < 4; ++j) {
        float4 a = p4[j * NT + tid];
        k[j * 4 + 0] = a.x; k[j * 4 + 1] = a.y;
        k[j * 4 + 2] = a.z; k[j * 4 + 3] = a.w;
    }
    if (tid == 0) selCnt = 0;

    // ---- phase 1: per-wave ballot-compacted filter (no atomics, no pre-barrier) ----
    int off = 0;
#pragma unroll
    for (int s = 0; s < EPT; ++s) {
        bool f = k[s] > C0;
        unsigned long long m = __ballot(f);
        if (f) {
            int pos = off + __popcll(m & lt);
            if (pos < WCAP) cand[wave * WCAP + pos] = k[s];
        }
        off += __popcll(m);
    }
    if (lane == 0) wcnt[wave] = (unsigned)off;
    __syncthreads();  // B1: cand/wcnt/selCnt visible

    const unsigned w0 = wcnt[0], w1 = wcnt[1], w2 = wcnt[2], w3 = wcnt[3];
    const unsigned total = w0 + w1 + w2 + w3;
    const bool fastok = (w0 <= WCAP) && (w1 <= WCAP) && (w2 <= WCAP) &&
                        (w3 <= WCAP) && (total >= KSEL);

    unsigned Tkey;
    int n_gt, n_eq;
    if (fastok) {
        // ---- phase 2 (common): every wave redundantly finds 8th-largest key ----
        // flat slot i: buffer b=i>>5, pos p=i&31; valid iff p < wcnt[b]
        float f0 = cand[lane];
        float f1 = cand[lane + 64];
        bool  v0 = (lane & 31) < wcnt[lane >> 5];
        bool  v1 = (lane & 31) < wcnt[2 + (lane >> 5)];
        unsigned c0 = v0 ? ordkey(f0) : 0u;
        unsigned c1 = v1 ? ordkey(f1) : 0u;
        unsigned T = 0xC0000000u;  // all candidates > 2.0 => key > 0xC0000000
#pragma unroll
        for (int b = 29; b >= 0; --b) {
            unsigned c = T | (1u << b);
            int n = __popcll(__ballot(c0 >= c)) + __popcll(__ballot(c1 >= c));
            if (n >= KSEL) T = c;
        }
        Tkey = T;
        n_gt = __popcll(__ballot(c0 > T)) + __popcll(__ballot(c1 > T));
        n_eq = __popcll(__ballot(c0 == T)) + __popcll(__ballot(c1 == T));
    } else {
        // ---- exact block-wide fallback (never on this input) ----
        unsigned ku[EPT];
#pragma unroll
        for (int s = 0; s < EPT; ++s) ku[s] = ordkey(k[s]);
        unsigned T = 0u;
        for (int b = 31; b >= 0; --b) {
            unsigned c = T | (1u << b);
            int n = 0;
#pragma unroll
            for (int s = 0; s < EPT; ++s) n += __popcll(__ballot(ku[s] >= c));
            if (lane == 0) swsum[wave] = (unsigned)n;
            __syncthreads();
            n = (int)(swsum[0] + swsum[1] + swsum[2] + swsum[3]);
            __syncthreads();
            if (n >= KSEL) T = c;
        }
        Tkey = T;
        int g = 0, e = 0;
#pragma unroll
        for (int s = 0; s < EPT; ++s) {
            g += __popcll(__ballot(ku[s] > T));
            e += __popcll(__ballot(ku[s] == T));
        }
        if (lane == 0) swsum[wave] = ((unsigned)g << 16) | (unsigned)e;
        __syncthreads();
        unsigned tt = swsum[0] + swsum[1] + swsum[2] + swsum[3];
        __syncthreads();
        n_gt = (int)(tt >> 16);
        n_eq = (int)(tt & 0xFFFFu);
    }

    const float Tf = unkey(Tkey);
    const int   Q  = KSEL - n_gt;   // # of ==T elements to select (>=1, <= n_eq)
    int X;                          // select ==T elems with gi <= X
    if (n_eq == Q) {
        X = ROW_LEN;                // all ==T selected (common: n_eq == Q == small)
    } else {
        // rare exact path: Q-th smallest gi among elements == T (block-uniform branch)
        int Xl = 0;
        for (int b = 11; b >= 0; --b) {
            int c = Xl | (1 << b);
            int n = 0;
#pragma unroll
            for (int s = 0; s < EPT; ++s) {
                int gi = (tid << 2) + (((s >> 2) << 10) | (s & 3));
                n += __popcll(__ballot(k[s] == Tf && gi < c));
            }
            if (lane == 0) swsum[wave] = (unsigned)n;
            __syncthreads();
            n = (int)(swsum[0] + swsum[1] + swsum[2] + swsum[3]);
            __syncthreads();
            if (n < Q) Xl = c;
        }
        X = Xl;
    }

    // ---- phase 3: exactly 8 locally-decided winners -> LDS, sort by gi, write ----
#pragma unroll
    for (int s = 0; s < EPT; ++s) {
        int gi = (tid << 2) + (((s >> 2) << 10) | (s & 3));
        bool sel = (k[s] > Tf) || (k[s] == Tf && gi <= X);
        if (sel) {
            int pos = atomicAdd(&selCnt, 1) & (KSEL - 1);  // mask = OOB insurance
            selV[pos]  = k[s];
            selGi[pos] = gi;
        }
    }
    __syncthreads();  // B2

    if (tid == 0) {
        float v[8]; int g[8];
#pragma unroll
        for (int i = 0; i < 8; ++i) { v[i] = selV[i]; g[i] = selGi[i]; }
#define CSW(i, j) if (g[i] > g[j]) { int tg = g[i]; g[i] = g[j]; g[j] = tg; \
                                     float tv = v[i]; v[i] = v[j]; v[j] = tv; }
        CSW(0,1) CSW(2,3) CSW(4,5) CSW(6,7)
        CSW(0,2) CSW(1,3) CSW(4,6) CSW(5,7)
        CSW(1,2) CSW(5,6)
        CSW(0,4) CSW(1,5) CSW(2,6) CSW(3,7)
        CSW(2,4) CSW(3,5)
        CSW(1,2) CSW(3,4) CSW(5,6)
        float4* o4 = reinterpret_cast<float4*>(out + (size_t)row * KSEL);
        o4[0] = make_float4(v[0], v[1], v[2], v[3]);
        o4[1] = make_float4(v[4], v[5], v[6], v[7]);
    }
}

extern "C" void kernel_launch(void* const* d_in, const int* in_sizes, int n_in,
                              void* d_out, int out_size, void* d_ws, size_t ws_size,
                              hipStream_t stream) {
    const float* in  = (const float*)d_in[0];
    float*       out = (float*)d_out;
    const int rows = in_sizes[0] / ROW_LEN;  // 32*512 = 16384
    kmax_kernel<<<rows, NT, 0, stream>>>(in, out);
}